// Round 7
// baseline (11.305 us; speedup 1.0000x reference)
//
#include <hip/hip_runtime.h>

// loss = (1/T) * (1 - mean_i p_i),  p_i = dot(a_i,b_i) / (max(||a_i||,eps)*max(||b_i||,eps))
// B=4096, D=512, T=0.5, eps=1e-12
//
// Two plain graph nodes:
//  kernel 1: 256 blocks x 512 threads, 2 rows/wave, wave butterfly reduce,
//            LDS reduce of 8 wave sums -> ONE partial per block (256 total)
//  kernel 2: 1 block x 64 threads (single wave): lane l loads float4
//            partial[4l..4l+3], butterfly reduce, write loss.
// All reduction orders fixed -> bit-deterministic. No cross-call state.

#define BATCH 4096
#define DIM 512
#define THREADS 512            // 8 waves/block
#define WAVES_PER_BLOCK 8
#define ROWS_PER_WAVE 2
#define ROWS_PER_BLOCK (WAVES_PER_BLOCK * ROWS_PER_WAVE)   // 16
#define NBLOCKS (BATCH / ROWS_PER_BLOCK)                   // 256

__global__ void __launch_bounds__(THREADS)
pair_cosine_partial(const float* __restrict__ a,
                    const float* __restrict__ b,
                    float* __restrict__ partial) {
    const int wave = threadIdx.x >> 6;          // 0..7
    const int lane = threadIdx.x & 63;
    const int r0   = (blockIdx.x * WAVES_PER_BLOCK + wave) * ROWS_PER_WAVE;

    // Each wave handles rows r0, r0+1. Row = 128 float4. Lane l covers
    // float4[l], float4[l+64] of each row -> 8 independent 16B loads/thread.
    const float4* a4 = reinterpret_cast<const float4*>(a) + (size_t)r0 * (DIM / 4);
    const float4* b4 = reinterpret_cast<const float4*>(b) + (size_t)r0 * (DIM / 4);

    float4 av0 = a4[lane];
    float4 av1 = a4[lane + 64];
    float4 av2 = a4[lane + 128];
    float4 av3 = a4[lane + 192];
    float4 bv0 = b4[lane];
    float4 bv1 = b4[lane + 64];
    float4 bv2 = b4[lane + 128];
    float4 bv3 = b4[lane + 192];

    // row r0
    float dot0 = av0.x*bv0.x + av0.y*bv0.y + av0.z*bv0.z + av0.w*bv0.w
               + av1.x*bv1.x + av1.y*bv1.y + av1.z*bv1.z + av1.w*bv1.w;
    float na0  = av0.x*av0.x + av0.y*av0.y + av0.z*av0.z + av0.w*av0.w
               + av1.x*av1.x + av1.y*av1.y + av1.z*av1.z + av1.w*av1.w;
    float nb0  = bv0.x*bv0.x + bv0.y*bv0.y + bv0.z*bv0.z + bv0.w*bv0.w
               + bv1.x*bv1.x + bv1.y*bv1.y + bv1.z*bv1.z + bv1.w*bv1.w;
    // row r0+1
    float dot1 = av2.x*bv2.x + av2.y*bv2.y + av2.z*bv2.z + av2.w*bv2.w
               + av3.x*bv3.x + av3.y*bv3.y + av3.z*bv3.z + av3.w*bv3.w;
    float na1  = av2.x*av2.x + av2.y*av2.y + av2.z*av2.z + av2.w*av2.w
               + av3.x*av3.x + av3.y*av3.y + av3.z*av3.z + av3.w*av3.w;
    float nb1  = bv2.x*bv2.x + bv2.y*bv2.y + bv2.z*bv2.z + bv2.w*bv2.w
               + bv3.x*bv3.x + bv3.y*bv3.y + bv3.z*bv3.z + bv3.w*bv3.w;

    #pragma unroll
    for (int off = 32; off > 0; off >>= 1) {
        dot0 += __shfl_xor(dot0, off);
        na0  += __shfl_xor(na0, off);
        nb0  += __shfl_xor(nb0, off);
        dot1 += __shfl_xor(dot1, off);
        na1  += __shfl_xor(na1, off);
        nb1  += __shfl_xor(nb1, off);
    }

    __shared__ float s[WAVES_PER_BLOCK];
    if (lane == 0) {
        float d0 = fmaxf(sqrtf(na0), 1e-12f) * fmaxf(sqrtf(nb0), 1e-12f);
        float d1 = fmaxf(sqrtf(na1), 1e-12f) * fmaxf(sqrtf(nb1), 1e-12f);
        s[wave] = dot0 / d0 + dot1 / d1;
    }
    __syncthreads();
    if (threadIdx.x == 0) {
        float p = 0.f;
        #pragma unroll
        for (int i = 0; i < WAVES_PER_BLOCK; ++i) p += s[i];
        partial[blockIdx.x] = p;
    }
}

__global__ void __launch_bounds__(64)
finalize_loss(const float* __restrict__ partial,
              float* __restrict__ out) {
    // 256 partials = 64 float4; lane l loads float4[l]
    const int lane = threadIdx.x;
    float4 v4 = reinterpret_cast<const float4*>(partial)[lane];
    float v = v4.x + v4.y + v4.z + v4.w;

    #pragma unroll
    for (int off = 32; off > 0; off >>= 1) {
        v += __shfl_xor(v, off);
    }
    if (lane == 0) {
        float mean_p = v / (float)BATCH;
        out[0] = (1.0f - mean_p) * 2.0f;   // (1 - mean_p) / 0.5
    }
}

extern "C" void kernel_launch(void* const* d_in, const int* in_sizes, int n_in,
                              void* d_out, int out_size, void* d_ws, size_t ws_size,
                              hipStream_t stream) {
    const float* a = (const float*)d_in[0];   // emb_i [B, D]
    const float* b = (const float*)d_in[1];   // emb_j [B, D]
    float* out = (float*)d_out;
    float* partial = (float*)d_ws;            // NBLOCKS floats (1 KB)

    pair_cosine_partial<<<NBLOCKS, THREADS, 0, stream>>>(a, b, partial);
    finalize_loss<<<1, 64, 0, stream>>>(partial, out);
}